// Round 7
// baseline (380.563 us; speedup 1.0000x reference)
//
#include <hip/hip_runtime.h>

// DoubleSin via bf16 MFMA (16x16x32), zero-LDS.
// Round-7: ILP x2 — each wave processes a 32-point super-tile (2 independent
// 16-point MFMA tiles) per iteration. Occupancy is register-capped at
// 2 waves/SIMD (128 weight-fragment VGPRs are irreducible at the required
// precision), so the fix for VALUBusy=51% is intra-wave ILP, not more waves.
// Grid back to 512 (2048 waves = exactly the 2/SIMD cap; 1024 blocks only
// doubled preamble cost — round-6 regression).
// Structure: D = W'.H (weights as A-operand); D registers of layer L are
// exactly the B fragment of layer L+1. Snake scales folded into weights;
// activation g(q) = q + sin^2(q). 3-term bf16 split Wh*Bh + Wh*Bl + Wl*Bh.

typedef __attribute__((ext_vector_type(8))) short bf8v;
typedef __attribute__((ext_vector_type(4))) float f4v;

union BF8U { bf8v v; unsigned d[4]; unsigned short s[8]; };

__device__ __forceinline__ unsigned short f2bf(float f) {   // preamble only
    unsigned u = __builtin_bit_cast(unsigned, f);
    u += 0x7fffu + ((u >> 16) & 1u);
    return (unsigned short)(u >> 16);
}
__device__ __forceinline__ float bf2f(unsigned short b) {
    return __builtin_bit_cast(float, (unsigned)b << 16);
}
__device__ __forceinline__ unsigned cvt_pk_bf16(float lo, float hi) {
    unsigned r;
    asm("v_cvt_pk_bf16_f32 %0, %1, %2" : "=v"(r) : "v"(lo), "v"(hi));
    return r;
}

#define MFMA(a, b, c) __builtin_amdgcn_mfma_f32_16x16x32_bf16((a), (b), (c), 0, 0, 0)

// g(q) = q + sin^2 q on all 16 accs, then build hi/lo B fragments via cvt_pk
__device__ __forceinline__ void act_and_frags(f4v (&acc)[4], bf8v (&Bh)[2], bf8v (&Bl)[2]) {
    #pragma unroll
    for (int t = 0; t < 4; ++t) {
        #pragma unroll
        for (int j = 0; j < 4; ++j) {
            float q = acc[t][j];
            float s = __sinf(q);
            acc[t][j] = fmaf(s, s, q);
        }
    }
    #pragma unroll
    for (int s2 = 0; s2 < 2; ++s2) {
        BF8U h, l;
        #pragma unroll
        for (int p = 0; p < 4; ++p) {
            const int t = 2 * s2 + (p >> 1);
            const int j0 = (p & 1) * 2;
            const float v0 = acc[t][j0], v1 = acc[t][j0 + 1];
            const unsigned hd = cvt_pk_bf16(v0, v1);      // lo16=bf(v0), hi16=bf(v1)
            h.d[p] = hd;
            const float r0 = v0 - __builtin_bit_cast(float, hd << 16);
            const float r1 = v1 - __builtin_bit_cast(float, hd & 0xffff0000u);
            l.d[p] = cvt_pk_bf16(r0, r1);
        }
        Bh[s2] = h.v; Bl[s2] = l.v;
    }
}

template <int ACCUM>
__global__ __launch_bounds__(256, 2) void mlp_branch(
    const float* __restrict__ x,
    const float* __restrict__ W1, const float* __restrict__ b1, const float* __restrict__ a1,
    const float* __restrict__ W2, const float* __restrict__ b2, const float* __restrict__ a2,
    const float* __restrict__ W3, const float* __restrict__ b3, const float* __restrict__ a3,
    const float* __restrict__ W4, const float* __restrict__ b4,
    float* __restrict__ out, int n, float xscale)
{
    const int lane = threadIdx.x & 63;
    const int col  = lane & 15;
    const int g    = lane >> 4;
    const int wid  = (int)((blockIdx.x * blockDim.x + threadIdx.x) >> 6);
    const int nwaves = (int)((gridDim.x * blockDim.x) >> 6);
    const int nst = n >> 5;                 // 32-point super-tiles

    const bf8v z8 = {0, 0, 0, 0, 0, 0, 0, 0};

    // ---------------- preamble: fold params, build weight fragments --------
    // Layer 1 (VALU): q1[ch] = (a1*W1)[ch] * x + (a1*b1)[ch], ch = 16t+4g+j
    f4v w1p[4], b1p[4];
    #pragma unroll
    for (int t = 0; t < 4; ++t) {
        const int c0 = 16 * t + 4 * g;
        const f4v a1v = *(const f4v*)(a1 + c0);
        w1p[t] = a1v * *(const f4v*)(W1 + c0);
        b1p[t] = a1v * *(const f4v*)(b1 + c0);
    }

    // Layers 2,3 fragments: W'[o][k] = aout[o] * W[o][k] / ain[k]
    bf8v W2h[4][2], W2l[4][2], W3h[4][2], W3l[4][2];
    #pragma unroll
    for (int L = 0; L < 2; ++L) {
        const float* W    = L ? W3 : W2;
        const float* aout = L ? a3 : a2;
        const float* ain  = L ? a2 : a1;
        #pragma unroll
        for (int s = 0; s < 2; ++s) {
            const int kb = 32 * s + 4 * g;
            const f4v aia = *(const f4v*)(ain + kb);
            const f4v aib = *(const f4v*)(ain + kb + 16);
            float ra[8];
            #pragma unroll
            for (int j = 0; j < 4; ++j) { ra[j] = 1.0f / aia[j]; ra[4 + j] = 1.0f / aib[j]; }
            #pragma unroll
            for (int t = 0; t < 4; ++t) {
                const int o = 16 * t + col;
                const f4v wa = *(const f4v*)(W + o * 64 + kb);
                const f4v wb = *(const f4v*)(W + o * 64 + kb + 16);
                const float ao = aout[o];
                bf8v hh = z8, ll = z8;
                #pragma unroll
                for (int j = 0; j < 8; ++j) {
                    const float wv = (j < 4) ? wa[j & 3] : wb[j & 3];
                    const float wp = ao * wv * ra[j];
                    unsigned short hb = f2bf(wp);
                    hh[j] = (short)hb;
                    ll[j] = (short)f2bf(wp - bf2f(hb));
                }
                if (L == 0) { W2h[t][s] = hh; W2l[t][s] = ll; }
                else        { W3h[t][s] = hh; W3l[t][s] = ll; }
            }
        }
    }

    // scaled biases and w4' = w4 / a3 (per-lane quad = 16t + 4g + j)
    f4v bias2[4], bias3[4], w4p[4];
    #pragma unroll
    for (int t = 0; t < 4; ++t) {
        const int c0 = 16 * t + 4 * g;
        bias2[t] = *(const f4v*)(b2 + c0) * *(const f4v*)(a2 + c0);
        bias3[t] = *(const f4v*)(b3 + c0) * *(const f4v*)(a3 + c0);
        w4p[t]   = *(const f4v*)(W4 + c0) / *(const f4v*)(a3 + c0);
    }
    const float b4v = b4[0];

    // ---------------- main loop over 32-point super-tiles ------------------
    int st = wid;
    if (st >= nst) return;
    float xA = xscale * x[st * 32 + col];
    float xB = xscale * x[st * 32 + 16 + col];
    float oc = (ACCUM && lane < 32) ? out[st * 32 + (lane & 31)] : 0.0f;

    while (st < nst) {
        const int snext = st + nwaves;
        float xAn = 0.0f, xBn = 0.0f, on = 0.0f;
        if (snext < nst) {
            xAn = xscale * x[snext * 32 + col];
            xBn = xscale * x[snext * 32 + 16 + col];
            if (ACCUM && lane < 32) on = out[snext * 32 + (lane & 31)];
        }

        // ---- layer 1 (fp32 VALU), both tiles ----
        f4v accA[4], accB[4];
        #pragma unroll
        for (int t = 0; t < 4; ++t) {
            #pragma unroll
            for (int j = 0; j < 4; ++j) {
                accA[t][j] = fmaf(w1p[t][j], xA, b1p[t][j]);
                accB[t][j] = fmaf(w1p[t][j], xB, b1p[t][j]);
            }
        }
        bf8v BhA[2], BlA[2], BhB[2], BlB[2];
        act_and_frags(accA, BhA, BlA);
        act_and_frags(accB, BhB, BlB);

        // ---- layer 2, both tiles ----
        f4v acc2A[4], acc2B[4];
        #pragma unroll
        for (int t = 0; t < 4; ++t) {
            f4v dA = bias2[t], dB = bias2[t];
            #pragma unroll
            for (int s = 0; s < 2; ++s) {
                dA = MFMA(W2h[t][s], BhA[s], dA);
                dB = MFMA(W2h[t][s], BhB[s], dB);
                dA = MFMA(W2h[t][s], BlA[s], dA);
                dB = MFMA(W2h[t][s], BlB[s], dB);
                dA = MFMA(W2l[t][s], BhA[s], dA);
                dB = MFMA(W2l[t][s], BhB[s], dB);
            }
            acc2A[t] = dA; acc2B[t] = dB;
        }
        act_and_frags(acc2A, BhA, BlA);
        act_and_frags(acc2B, BhB, BlB);

        // ---- layer 3, both tiles ----
        #pragma unroll
        for (int t = 0; t < 4; ++t) {
            f4v dA = bias3[t], dB = bias3[t];
            #pragma unroll
            for (int s = 0; s < 2; ++s) {
                dA = MFMA(W3h[t][s], BhA[s], dA);
                dB = MFMA(W3h[t][s], BhB[s], dB);
                dA = MFMA(W3h[t][s], BlA[s], dA);
                dB = MFMA(W3h[t][s], BlB[s], dB);
                dA = MFMA(W3l[t][s], BhA[s], dA);
                dB = MFMA(W3l[t][s], BhB[s], dB);
            }
            accA[t] = dA; accB[t] = dB;
        }
        #pragma unroll
        for (int t = 0; t < 4; ++t) {
            #pragma unroll
            for (int j = 0; j < 4; ++j) {
                float qA = accA[t][j], qB = accB[t][j];
                float sA = __sinf(qA), sB = __sinf(qB);
                accA[t][j] = fmaf(sA, sA, qA);
                accB[t][j] = fmaf(sB, sB, qB);
            }
        }

        // ---- layer 4, both tiles ----
        float pA = 0.0f, pB = 0.0f;
        #pragma unroll
        for (int t = 0; t < 4; ++t) {
            #pragma unroll
            for (int j = 0; j < 4; ++j) {
                pA = fmaf(w4p[t][j], accA[t][j], pA);
                pB = fmaf(w4p[t][j], accB[t][j], pB);
            }
        }
        pA += __shfl_xor(pA, 16); pA += __shfl_xor(pA, 32);
        pB += __shfl_xor(pB, 16); pB += __shfl_xor(pB, 32);

        const float pW = (lane < 16) ? pA : pB;
        if (lane < 32) out[st * 32 + (lane & 31)] = pW + b4v + oc;

        st = snext; xA = xAn; xB = xBn; oc = on;
    }
}

extern "C" void kernel_launch(void* const* d_in, const int* in_sizes, int n_in,
                              void* d_out, int out_size, void* d_ws, size_t ws_size,
                              hipStream_t stream) {
    const float* x   = (const float*)d_in[0];
    const float* W1a = (const float*)d_in[1];
    const float* b1a = (const float*)d_in[2];
    const float* a1a = (const float*)d_in[3];
    const float* W2a = (const float*)d_in[4];
    const float* b2a = (const float*)d_in[5];
    const float* a2a = (const float*)d_in[6];
    const float* W3a = (const float*)d_in[7];
    const float* b3a = (const float*)d_in[8];
    const float* a3a = (const float*)d_in[9];
    const float* W4a = (const float*)d_in[10];
    const float* b4a = (const float*)d_in[11];
    const float* W1b = (const float*)d_in[12];
    const float* b1b = (const float*)d_in[13];
    const float* a1b = (const float*)d_in[14];
    const float* W2b = (const float*)d_in[15];
    const float* b2b = (const float*)d_in[16];
    const float* a2b = (const float*)d_in[17];
    const float* W3b = (const float*)d_in[18];
    const float* b3b = (const float*)d_in[19];
    const float* a3b = (const float*)d_in[20];
    const float* W4b = (const float*)d_in[21];
    const float* b4b = (const float*)d_in[22];

    const int n = in_sizes[0];
    float* out = (float*)d_out;

    mlp_branch<0><<<512, 256, 0, stream>>>(x, W1a, b1a, a1a, W2a, b2a, a2a,
                                           W3a, b3a, a3a, W4a, b4a,
                                           out, n, 1.0f);
    mlp_branch<1><<<512, 256, 0, stream>>>(x, W1b, b1b, a1b, W2b, b2b, a2b,
                                           W3b, b3b, a3b, W4b, b4b,
                                           out, n, 2.0f);
}

// Round 8
// 287.904 us; speedup vs baseline: 1.3218x; 1.3218x over previous
//
#include <hip/hip_runtime.h>

// DoubleSin via bf16 MFMA (16x16x32), zero-LDS.
// Round-8: branch fusion. Round-7 lesson: ILP x2 spilled (live state ~270 regs
// > 256 budget at 2 waves/SIMD) -> FETCH/WRITE ballooned, VALUBusy fell. The
// per-wave structure reverts to round-4 (best: 183 us/dispatch, no spills).
// The win here: the two MLP branches were serialized as 2 dispatches
// (183+181 us); they are independent, so ONE dispatch of 1024 blocks runs
// both concurrently (blockIdx&1 selects branch; each block carries only its
// branch's weights -> same register footprint). Both branches accumulate into
// zeroed out via HW f32 atomic add (exactly 2 adds/element, bitwise
// commutative -> deterministic). xscale folded into the layer-1 weight fold.
// Structure: D = W'.H (weights as A-operand); D registers of layer L are the
// B fragment of layer L+1. Snake scales folded into weights; activation
// g(q) = q + sin^2(q). 3-term bf16 split Wh*Bh + Wh*Bl + Wl*Bh.

typedef __attribute__((ext_vector_type(8))) short bf8v;
typedef __attribute__((ext_vector_type(4))) float f4v;

union BF8U { bf8v v; unsigned d[4]; unsigned short s[8]; };

__device__ __forceinline__ unsigned short f2bf(float f) {   // preamble only
    unsigned u = __builtin_bit_cast(unsigned, f);
    u += 0x7fffu + ((u >> 16) & 1u);
    return (unsigned short)(u >> 16);
}
__device__ __forceinline__ float bf2f(unsigned short b) {
    return __builtin_bit_cast(float, (unsigned)b << 16);
}
__device__ __forceinline__ unsigned cvt_pk_bf16(float lo, float hi) {
    unsigned r;
    asm("v_cvt_pk_bf16_f32 %0, %1, %2" : "=v"(r) : "v"(lo), "v"(hi));
    return r;
}

#define MFMA(a, b, c) __builtin_amdgcn_mfma_f32_16x16x32_bf16((a), (b), (c), 0, 0, 0)

// g(q) = q + sin^2 q on all 16 accs, then build hi/lo B fragments via cvt_pk
__device__ __forceinline__ void act_and_frags(f4v (&acc)[4], bf8v (&Bh)[2], bf8v (&Bl)[2]) {
    #pragma unroll
    for (int t = 0; t < 4; ++t) {
        #pragma unroll
        for (int j = 0; j < 4; ++j) {
            float q = acc[t][j];
            float s = __sinf(q);
            acc[t][j] = fmaf(s, s, q);
        }
    }
    #pragma unroll
    for (int s2 = 0; s2 < 2; ++s2) {
        BF8U h, l;
        #pragma unroll
        for (int p = 0; p < 4; ++p) {
            const int t = 2 * s2 + (p >> 1);
            const int j0 = (p & 1) * 2;
            const float v0 = acc[t][j0], v1 = acc[t][j0 + 1];
            const unsigned hd = cvt_pk_bf16(v0, v1);      // lo16=bf(v0), hi16=bf(v1)
            h.d[p] = hd;
            const float r0 = v0 - __builtin_bit_cast(float, hd << 16);
            const float r1 = v1 - __builtin_bit_cast(float, hd & 0xffff0000u);
            l.d[p] = cvt_pk_bf16(r0, r1);
        }
        Bh[s2] = h.v; Bl[s2] = l.v;
    }
}

__global__ __launch_bounds__(256, 2) void mlp_fused(
    const float* __restrict__ x,
    const float* __restrict__ W1a, const float* __restrict__ b1a, const float* __restrict__ a1a,
    const float* __restrict__ W2a, const float* __restrict__ b2a, const float* __restrict__ a2a,
    const float* __restrict__ W3a, const float* __restrict__ b3a, const float* __restrict__ a3a,
    const float* __restrict__ W4a, const float* __restrict__ b4a,
    const float* __restrict__ W1b, const float* __restrict__ b1b, const float* __restrict__ a1b,
    const float* __restrict__ W2b, const float* __restrict__ b2b, const float* __restrict__ a2b,
    const float* __restrict__ W3b, const float* __restrict__ b3b, const float* __restrict__ a3b,
    const float* __restrict__ W4b, const float* __restrict__ b4b,
    float* __restrict__ out, int n)
{
    const int lane = threadIdx.x & 63;
    const int col  = lane & 15;
    const int g    = lane >> 4;
    const int br   = (int)(blockIdx.x & 1);
    const int sub  = (int)(blockIdx.x >> 1);
    const int wid  = sub * 4 + (int)(threadIdx.x >> 6);
    const int nwaves = (int)((gridDim.x >> 1) << 2);     // waves per branch
    const int ntiles = n >> 4;
    const float xscale = br ? 2.0f : 1.0f;

    const float* W1 = br ? W1b : W1a;  const float* b1 = br ? b1b : b1a;  const float* a1 = br ? a1b : a1a;
    const float* W2 = br ? W2b : W2a;  const float* b2 = br ? b2b : b2a;  const float* a2 = br ? a2b : a2a;
    const float* W3 = br ? W3b : W3a;  const float* b3 = br ? b3b : b3a;  const float* a3 = br ? a3b : a3a;
    const float* W4 = br ? W4b : W4a;  const float* b4 = br ? b4b : b4a;

    const bf8v z8 = {0, 0, 0, 0, 0, 0, 0, 0};

    // ---------------- preamble: fold params, build weight fragments --------
    // Layer 1 (VALU): q1[ch] = (a1*W1*xscale)[ch] * x + (a1*b1)[ch]
    f4v w1p[4], b1p[4];
    #pragma unroll
    for (int t = 0; t < 4; ++t) {
        const int c0 = 16 * t + 4 * g;
        const f4v a1v = *(const f4v*)(a1 + c0);
        w1p[t] = (a1v * xscale) * *(const f4v*)(W1 + c0);
        b1p[t] = a1v * *(const f4v*)(b1 + c0);
    }

    // Layers 2,3 fragments: W'[o][k] = aout[o] * W[o][k] / ain[k]
    bf8v W2h[4][2], W2l[4][2], W3h[4][2], W3l[4][2];
    #pragma unroll
    for (int L = 0; L < 2; ++L) {
        const float* W    = L ? W3 : W2;
        const float* aout = L ? a3 : a2;
        const float* ain  = L ? a2 : a1;
        #pragma unroll
        for (int s = 0; s < 2; ++s) {
            const int kb = 32 * s + 4 * g;
            const f4v aia = *(const f4v*)(ain + kb);
            const f4v aib = *(const f4v*)(ain + kb + 16);
            float ra[8];
            #pragma unroll
            for (int j = 0; j < 4; ++j) { ra[j] = 1.0f / aia[j]; ra[4 + j] = 1.0f / aib[j]; }
            #pragma unroll
            for (int t = 0; t < 4; ++t) {
                const int o = 16 * t + col;
                const f4v wa = *(const f4v*)(W + o * 64 + kb);
                const f4v wb = *(const f4v*)(W + o * 64 + kb + 16);
                const float ao = aout[o];
                bf8v hh = z8, ll = z8;
                #pragma unroll
                for (int j = 0; j < 8; ++j) {
                    const float wv = (j < 4) ? wa[j & 3] : wb[j & 3];
                    const float wp = ao * wv * ra[j];
                    unsigned short hb = f2bf(wp);
                    hh[j] = (short)hb;
                    ll[j] = (short)f2bf(wp - bf2f(hb));
                }
                if (L == 0) { W2h[t][s] = hh; W2l[t][s] = ll; }
                else        { W3h[t][s] = hh; W3l[t][s] = ll; }
            }
        }
    }

    // scaled biases and w4' = w4 / a3 (per-lane quad = 16t + 4g + j)
    f4v bias2[4], bias3[4], w4p[4];
    #pragma unroll
    for (int t = 0; t < 4; ++t) {
        const int c0 = 16 * t + 4 * g;
        bias2[t] = *(const f4v*)(b2 + c0) * *(const f4v*)(a2 + c0);
        bias3[t] = *(const f4v*)(b3 + c0) * *(const f4v*)(a3 + c0);
        w4p[t]   = *(const f4v*)(W4 + c0) / *(const f4v*)(a3 + c0);
    }
    const float b4v = b4[0];

    // ---------------- main loop over 16-point tiles ------------------------
    int tile = wid;
    if (tile >= ntiles) return;
    float xc = x[tile * 16 + col];

    while (tile < ntiles) {
        const int tnext = tile + nwaves;
        float xn = 0.0f;
        if (tnext < ntiles) xn = x[tnext * 16 + col];

        // ---- layer 1 (fp32 VALU) ----
        f4v acc[4];
        #pragma unroll
        for (int t = 0; t < 4; ++t) {
            #pragma unroll
            for (int j = 0; j < 4; ++j) acc[t][j] = fmaf(w1p[t][j], xc, b1p[t][j]);
        }
        bf8v Bh[2], Bl[2];
        act_and_frags(acc, Bh, Bl);    // g1 -> fragments

        // ---- layer 2 ----
        f4v acc2[4];
        #pragma unroll
        for (int t = 0; t < 4; ++t) {
            f4v d = bias2[t];
            #pragma unroll
            for (int s = 0; s < 2; ++s) {
                d = MFMA(W2h[t][s], Bh[s], d);
                d = MFMA(W2h[t][s], Bl[s], d);
                d = MFMA(W2l[t][s], Bh[s], d);
            }
            acc2[t] = d;
        }
        act_and_frags(acc2, Bh, Bl);   // g2 -> fragments

        // ---- layer 3 ----
        #pragma unroll
        for (int t = 0; t < 4; ++t) {
            f4v d = bias3[t];
            #pragma unroll
            for (int s = 0; s < 2; ++s) {
                d = MFMA(W3h[t][s], Bh[s], d);
                d = MFMA(W3h[t][s], Bl[s], d);
                d = MFMA(W3l[t][s], Bh[s], d);
            }
            acc[t] = d;
        }
        #pragma unroll
        for (int t = 0; t < 4; ++t) {
            #pragma unroll
            for (int j = 0; j < 4; ++j) {
                float q = acc[t][j];
                float s = __sinf(q);
                acc[t][j] = fmaf(s, s, q);
            }
        }

        // ---- layer 4 ----
        float p = 0.0f;
        #pragma unroll
        for (int t = 0; t < 4; ++t) {
            #pragma unroll
            for (int j = 0; j < 4; ++j) p = fmaf(w4p[t][j], acc[t][j], p);
        }
        p += __shfl_xor(p, 16);
        p += __shfl_xor(p, 32);

        if (lane < 16) unsafeAtomicAdd(&out[tile * 16 + col], p + b4v);

        tile = tnext; xc = xn;
    }
}

extern "C" void kernel_launch(void* const* d_in, const int* in_sizes, int n_in,
                              void* d_out, int out_size, void* d_ws, size_t ws_size,
                              hipStream_t stream) {
    const float* x   = (const float*)d_in[0];
    const float* W1a = (const float*)d_in[1];
    const float* b1a = (const float*)d_in[2];
    const float* a1a = (const float*)d_in[3];
    const float* W2a = (const float*)d_in[4];
    const float* b2a = (const float*)d_in[5];
    const float* a2a = (const float*)d_in[6];
    const float* W3a = (const float*)d_in[7];
    const float* b3a = (const float*)d_in[8];
    const float* a3a = (const float*)d_in[9];
    const float* W4a = (const float*)d_in[10];
    const float* b4a = (const float*)d_in[11];
    const float* W1b = (const float*)d_in[12];
    const float* b1b = (const float*)d_in[13];
    const float* a1b = (const float*)d_in[14];
    const float* W2b = (const float*)d_in[15];
    const float* b2b = (const float*)d_in[16];
    const float* a2b = (const float*)d_in[17];
    const float* W3b = (const float*)d_in[18];
    const float* b3b = (const float*)d_in[19];
    const float* a3b = (const float*)d_in[20];
    const float* W4b = (const float*)d_in[21];
    const float* b4b = (const float*)d_in[22];

    const int n = in_sizes[0];
    float* out = (float*)d_out;

    hipMemsetAsync(out, 0, (size_t)n * sizeof(float), stream);
    mlp_fused<<<1024, 256, 0, stream>>>(x,
                                        W1a, b1a, a1a, W2a, b2a, a2a,
                                        W3a, b3a, a3a, W4a, b4a,
                                        W1b, b1b, a1b, W2b, b2b, a2b,
                                        W3b, b3b, a3b, W4b, b4b,
                                        out, n);
}

// Round 9
// 237.089 us; speedup vs baseline: 1.6051x; 1.2143x over previous
//
#include <hip/hip_runtime.h>

// DoubleSin via bf16 MFMA (16x16x32), zero-LDS, fused branches.
// Round-9: drop the Wh*Bl MFMA term (activation-residual correction).
//  - act->fragment is now ONE v_cvt_pk_bf16_f32 per pair (RNE): the whole
//    lo-residual build (unpack/sub/cvt chain, ~80 VALU instr/tile) is gone,
//    and the act->MFMA critical path shrinks from 5-deep to 2-deep.
//  - MFMA per tile: 48 -> 32 (keep Wh*Bh + Wl*Bh; weight residual is free
//    per-tile since Wl fragments are preamble-built).
//  - Error model: activations truncated to bf16 (rel ~2^-10 rms), through
//    |W|<=0.125 64-term sums and two layers -> ~3-5e-3 added at the tail;
//    predicted absmax ~0.008 < 0.0199 threshold. If this fails, revert.
// Structure otherwise round-8: one dispatch, blockIdx&1 selects branch,
// unsafeAtomicAdd into zeroed out (exactly 2 adds/element, deterministic).

typedef __attribute__((ext_vector_type(8))) short bf8v;
typedef __attribute__((ext_vector_type(4))) float f4v;

union BF8U { bf8v v; unsigned d[4]; unsigned short s[8]; };

__device__ __forceinline__ unsigned short f2bf(float f) {   // preamble only
    unsigned u = __builtin_bit_cast(unsigned, f);
    u += 0x7fffu + ((u >> 16) & 1u);
    return (unsigned short)(u >> 16);
}
__device__ __forceinline__ float bf2f(unsigned short b) {
    return __builtin_bit_cast(float, (unsigned)b << 16);
}
__device__ __forceinline__ unsigned cvt_pk_bf16(float lo, float hi) {
    unsigned r;
    asm("v_cvt_pk_bf16_f32 %0, %1, %2" : "=v"(r) : "v"(lo), "v"(hi));
    return r;
}

#define MFMA(a, b, c) __builtin_amdgcn_mfma_f32_16x16x32_bf16((a), (b), (c), 0, 0, 0)

// g(q) = q + sin^2 q on all 16 accs, then build bf16 B fragments (hi only)
__device__ __forceinline__ void act_and_frags(f4v (&acc)[4], bf8v (&Bh)[2]) {
    #pragma unroll
    for (int t = 0; t < 4; ++t) {
        #pragma unroll
        for (int j = 0; j < 4; ++j) {
            float q = acc[t][j];
            float s = __sinf(q);
            acc[t][j] = fmaf(s, s, q);
        }
    }
    #pragma unroll
    for (int s2 = 0; s2 < 2; ++s2) {
        BF8U h;
        #pragma unroll
        for (int p = 0; p < 4; ++p) {
            const int t = 2 * s2 + (p >> 1);
            const int j0 = (p & 1) * 2;
            h.d[p] = cvt_pk_bf16(acc[t][j0], acc[t][j0 + 1]);
        }
        Bh[s2] = h.v;
    }
}

__global__ __launch_bounds__(256, 2) void mlp_fused(
    const float* __restrict__ x,
    const float* __restrict__ W1a, const float* __restrict__ b1a, const float* __restrict__ a1a,
    const float* __restrict__ W2a, const float* __restrict__ b2a, const float* __restrict__ a2a,
    const float* __restrict__ W3a, const float* __restrict__ b3a, const float* __restrict__ a3a,
    const float* __restrict__ W4a, const float* __restrict__ b4a,
    const float* __restrict__ W1b, const float* __restrict__ b1b, const float* __restrict__ a1b,
    const float* __restrict__ W2b, const float* __restrict__ b2b, const float* __restrict__ a2b,
    const float* __restrict__ W3b, const float* __restrict__ b3b, const float* __restrict__ a3b,
    const float* __restrict__ W4b, const float* __restrict__ b4b,
    float* __restrict__ out, int n)
{
    const int lane = threadIdx.x & 63;
    const int col  = lane & 15;
    const int g    = lane >> 4;
    const int br   = (int)(blockIdx.x & 1);
    const int sub  = (int)(blockIdx.x >> 1);
    const int wid  = sub * 4 + (int)(threadIdx.x >> 6);
    const int nwaves = (int)((gridDim.x >> 1) << 2);     // waves per branch
    const int ntiles = n >> 4;
    const float xscale = br ? 2.0f : 1.0f;

    const float* W1 = br ? W1b : W1a;  const float* b1 = br ? b1b : b1a;  const float* a1 = br ? a1b : a1a;
    const float* W2 = br ? W2b : W2a;  const float* b2 = br ? b2b : b2a;  const float* a2 = br ? a2b : a2a;
    const float* W3 = br ? W3b : W3a;  const float* b3 = br ? b3b : b3a;  const float* a3 = br ? a3b : a3a;
    const float* W4 = br ? W4b : W4a;  const float* b4 = br ? b4b : b4a;

    const bf8v z8 = {0, 0, 0, 0, 0, 0, 0, 0};

    // ---------------- preamble: fold params, build weight fragments --------
    // Layer 1 (VALU): q1[ch] = (a1*W1*xscale)[ch] * x + (a1*b1)[ch]
    f4v w1p[4], b1p[4];
    #pragma unroll
    for (int t = 0; t < 4; ++t) {
        const int c0 = 16 * t + 4 * g;
        const f4v a1v = *(const f4v*)(a1 + c0);
        w1p[t] = (a1v * xscale) * *(const f4v*)(W1 + c0);
        b1p[t] = a1v * *(const f4v*)(b1 + c0);
    }

    // Layers 2,3 fragments: W'[o][k] = aout[o] * W[o][k] / ain[k]
    bf8v W2h[4][2], W2l[4][2], W3h[4][2], W3l[4][2];
    #pragma unroll
    for (int L = 0; L < 2; ++L) {
        const float* W    = L ? W3 : W2;
        const float* aout = L ? a3 : a2;
        const float* ain  = L ? a2 : a1;
        #pragma unroll
        for (int s = 0; s < 2; ++s) {
            const int kb = 32 * s + 4 * g;
            const f4v aia = *(const f4v*)(ain + kb);
            const f4v aib = *(const f4v*)(ain + kb + 16);
            float ra[8];
            #pragma unroll
            for (int j = 0; j < 4; ++j) { ra[j] = 1.0f / aia[j]; ra[4 + j] = 1.0f / aib[j]; }
            #pragma unroll
            for (int t = 0; t < 4; ++t) {
                const int o = 16 * t + col;
                const f4v wa = *(const f4v*)(W + o * 64 + kb);
                const f4v wb = *(const f4v*)(W + o * 64 + kb + 16);
                const float ao = aout[o];
                bf8v hh = z8, ll = z8;
                #pragma unroll
                for (int j = 0; j < 8; ++j) {
                    const float wv = (j < 4) ? wa[j & 3] : wb[j & 3];
                    const float wp = ao * wv * ra[j];
                    unsigned short hb = f2bf(wp);
                    hh[j] = (short)hb;
                    ll[j] = (short)f2bf(wp - bf2f(hb));
                }
                if (L == 0) { W2h[t][s] = hh; W2l[t][s] = ll; }
                else        { W3h[t][s] = hh; W3l[t][s] = ll; }
            }
        }
    }

    // scaled biases and w4' = w4 / a3 (per-lane quad = 16t + 4g + j)
    f4v bias2[4], bias3[4], w4p[4];
    #pragma unroll
    for (int t = 0; t < 4; ++t) {
        const int c0 = 16 * t + 4 * g;
        bias2[t] = *(const f4v*)(b2 + c0) * *(const f4v*)(a2 + c0);
        bias3[t] = *(const f4v*)(b3 + c0) * *(const f4v*)(a3 + c0);
        w4p[t]   = *(const f4v*)(W4 + c0) / *(const f4v*)(a3 + c0);
    }
    const float b4v = b4[0];

    // ---------------- main loop over 16-point tiles ------------------------
    int tile = wid;
    if (tile >= ntiles) return;
    float xc = x[tile * 16 + col];

    while (tile < ntiles) {
        const int tnext = tile + nwaves;
        float xn = 0.0f;
        if (tnext < ntiles) xn = x[tnext * 16 + col];

        // ---- layer 1 (fp32 VALU) ----
        f4v acc[4];
        #pragma unroll
        for (int t = 0; t < 4; ++t) {
            #pragma unroll
            for (int j = 0; j < 4; ++j) acc[t][j] = fmaf(w1p[t][j], xc, b1p[t][j]);
        }
        bf8v Bh[2];
        act_and_frags(acc, Bh);        // g1 -> fragments (bf16 RNE)

        // ---- layer 2 ----
        f4v acc2[4];
        #pragma unroll
        for (int t = 0; t < 4; ++t) {
            f4v d = bias2[t];
            #pragma unroll
            for (int s = 0; s < 2; ++s) {
                d = MFMA(W2h[t][s], Bh[s], d);
                d = MFMA(W2l[t][s], Bh[s], d);
            }
            acc2[t] = d;
        }
        act_and_frags(acc2, Bh);       // g2 -> fragments

        // ---- layer 3 ----
        #pragma unroll
        for (int t = 0; t < 4; ++t) {
            f4v d = bias3[t];
            #pragma unroll
            for (int s = 0; s < 2; ++s) {
                d = MFMA(W3h[t][s], Bh[s], d);
                d = MFMA(W3l[t][s], Bh[s], d);
            }
            acc[t] = d;
        }
        #pragma unroll
        for (int t = 0; t < 4; ++t) {
            #pragma unroll
            for (int j = 0; j < 4; ++j) {
                float q = acc[t][j];
                float s = __sinf(q);
                acc[t][j] = fmaf(s, s, q);
            }
        }

        // ---- layer 4 ----
        float p = 0.0f;
        #pragma unroll
        for (int t = 0; t < 4; ++t) {
            #pragma unroll
            for (int j = 0; j < 4; ++j) p = fmaf(w4p[t][j], acc[t][j], p);
        }
        p += __shfl_xor(p, 16);
        p += __shfl_xor(p, 32);

        if (lane < 16) unsafeAtomicAdd(&out[tile * 16 + col], p + b4v);

        tile = tnext; xc = xn;
    }
}

extern "C" void kernel_launch(void* const* d_in, const int* in_sizes, int n_in,
                              void* d_out, int out_size, void* d_ws, size_t ws_size,
                              hipStream_t stream) {
    const float* x   = (const float*)d_in[0];
    const float* W1a = (const float*)d_in[1];
    const float* b1a = (const float*)d_in[2];
    const float* a1a = (const float*)d_in[3];
    const float* W2a = (const float*)d_in[4];
    const float* b2a = (const float*)d_in[5];
    const float* a2a = (const float*)d_in[6];
    const float* W3a = (const float*)d_in[7];
    const float* b3a = (const float*)d_in[8];
    const float* a3a = (const float*)d_in[9];
    const float* W4a = (const float*)d_in[10];
    const float* b4a = (const float*)d_in[11];
    const float* W1b = (const float*)d_in[12];
    const float* b1b = (const float*)d_in[13];
    const float* a1b = (const float*)d_in[14];
    const float* W2b = (const float*)d_in[15];
    const float* b2b = (const float*)d_in[16];
    const float* a2b = (const float*)d_in[17];
    const float* W3b = (const float*)d_in[18];
    const float* b3b = (const float*)d_in[19];
    const float* a3b = (const float*)d_in[20];
    const float* W4b = (const float*)d_in[21];
    const float* b4b = (const float*)d_in[22];

    const int n = in_sizes[0];
    float* out = (float*)d_out;

    hipMemsetAsync(out, 0, (size_t)n * sizeof(float), stream);
    mlp_fused<<<1024, 256, 0, stream>>>(x,
                                        W1a, b1a, a1a, W2a, b2a, a2a,
                                        W3a, b3a, a3a, W4a, b4a,
                                        W1b, b1b, a1b, W2b, b2b, a2b,
                                        W3b, b3b, a3b, W4b, b4b,
                                        out, n);
}